// Round 21
// baseline (263.577 us; speedup 1.0000x reference)
//
#include <hip/hip_runtime.h>
#include <hip/hip_bf16.h>
#include <math.h>

typedef __hip_bfloat16 bf16;
typedef __attribute__((ext_vector_type(8))) __bf16 bf16x8;
typedef __attribute__((ext_vector_type(4))) float f32x4;

__device__ __forceinline__ void gload_lds16(const void* g, void* l) {
  __builtin_amdgcn_global_load_lds(
      (const __attribute__((address_space(1))) unsigned int*)g,
      (__attribute__((address_space(3))) unsigned int*)l, 16, 0, 0);
}

// ---------------- fp32 -> bf16 conversion, 8 elems/thread ----------------
__global__ void cvt_bf16(const float* __restrict__ in, bf16* __restrict__ out, int n) {
  int idx = (blockIdx.x * blockDim.x + threadIdx.x) * 8;
  if (idx >= n) return;
  float4 v0 = *(const float4*)(in + idx);
  float4 v1 = *(const float4*)(in + idx + 4);
  alignas(16) bf16 tmp[8];
  tmp[0] = __float2bfloat16(v0.x); tmp[1] = __float2bfloat16(v0.y);
  tmp[2] = __float2bfloat16(v0.z); tmp[3] = __float2bfloat16(v0.w);
  tmp[4] = __float2bfloat16(v1.x); tmp[5] = __float2bfloat16(v1.y);
  tmp[6] = __float2bfloat16(v1.z); tmp[7] = __float2bfloat16(v1.w);
  *(uint4*)(out + idx) = *(const uint4*)tmp;
}

// ---- merged weight conversion + bias concat (one launch) ----
// Q weights/bias PRE-SCALED by 1/sqrt(HD)*log2(e) (exp2-domain scores).
__global__ void prep_w(const float* __restrict__ Wq, const float* __restrict__ Wk,
                       const float* __restrict__ Wv, const float* __restrict__ Wo,
                       const float* __restrict__ bq, const float* __restrict__ bk,
                       const float* __restrict__ bv,
                       bf16* __restrict__ wqkv, bf16* __restrict__ wo16,
                       float* __restrict__ b3) {
  const float QSCL = 0.125f * 1.4426950408889634f;
  const int bi = blockIdx.x;
  if (bi < 2048) {
    const int seg = bi >> 9;                        // 512 blocks per 1M-elem W
    const int idx = ((bi & 511) * 256 + threadIdx.x) * 8;
    const float* src = seg == 0 ? Wq : seg == 1 ? Wk : seg == 2 ? Wv : Wo;
    bf16* dst = seg < 3 ? wqkv + (size_t)seg * 1048576 : wo16;
    const float m = (seg == 0) ? QSCL : 1.0f;
    float4 v0 = *(const float4*)(src + idx);
    float4 v1 = *(const float4*)(src + idx + 4);
    alignas(16) bf16 tmp[8];
    tmp[0] = __float2bfloat16(v0.x * m); tmp[1] = __float2bfloat16(v0.y * m);
    tmp[2] = __float2bfloat16(v0.z * m); tmp[3] = __float2bfloat16(v0.w * m);
    tmp[4] = __float2bfloat16(v1.x * m); tmp[5] = __float2bfloat16(v1.y * m);
    tmp[6] = __float2bfloat16(v1.z * m); tmp[7] = __float2bfloat16(v1.w * m);
    *(uint4*)(dst + idx) = *(const uint4*)tmp;
  } else {
    const int i = (bi - 2048) * 256 + threadIdx.x;
    if (i < 3072)
      b3[i] = i < 1024 ? bq[i] * QSCL : i < 2048 ? bk[i - 1024] : bv[i - 2048];
  }
}

// ---------------- GEMM v6: barrier-minimal ring-3, BK=32, 2 blocks/CU --------
// (frozen from R20) BM=128, BN=256, BK=32. 8 waves (2x4), per-wave 64x64 C.
// SLOT 24KB, ring-3 = 72KB -> 2 blocks/CU = 16 waves/CU. One vmcnt+barrier
// per K-tile (counted vmcnt(3)); swizzle g^=r&3; setprio; L2-locality map.
template<int MODE>
__global__ __launch_bounds__(512, 2) void gemm6(
    const bf16* __restrict__ A, const bf16* __restrict__ Bw,
    const float* __restrict__ bias, void* __restrict__ Cout,
    bf16* __restrict__ vt, int N, int K)
{
  constexpr int SLOT = 12288;            // (128 + 256) * 32 bf16 = 24 KB
  __shared__ bf16 lds[3 * SLOT];         // 72 KB -> 2 blocks/CU
  const int tid = threadIdx.x;
  const int wave = tid >> 6, lane = tid & 63;
  const int lhi = lane >> 4, llo = lane & 15;
  const int wr = wave >> 2, wc = wave & 3;    // 2 x 4 wave grid

  const int xcd = blockIdx.x & 7;
  const int l = blockIdx.x >> 3;
  const int row0 = (xcd * 8 + (l & 7)) * 128;
  const int col0 = (l >> 3) * 256;

  auto stage = [&](int t) {
    bf16* s = &lds[(t % 3) * SLOT];
    const size_t k0 = (size_t)t << 5;
    {
      int i = tid;
      int r = i >> 2, gl = (i & 3) ^ (r & 3);
      gload_lds16(A + (size_t)(row0 + r) * K + k0 + gl * 8, s + i * 8);
    }
#pragma unroll
    for (int j = 0; j < 2; ++j) {
      int i = j * 512 + tid;
      int r = i >> 2, gl = (i & 3) ^ (r & 3);
      gload_lds16(Bw + (size_t)(col0 + r) * K + k0 + gl * 8, s + 4096 + i * 8);
    }
  };

  f32x4 acc[4][4] = {};
  const int T = K >> 5;

  stage(0); stage(1);
  asm volatile("s_waitcnt vmcnt(3)" ::: "memory");   // tile 0 complete
  __builtin_amdgcn_s_barrier();
  __builtin_amdgcn_sched_barrier(0);

  for (int t = 0; t < T; ++t) {
    const bf16* sa = &lds[(t % 3) * SLOT];
    const bf16* sb = sa + 4096;

    bf16x8 af[4], bfr[4];
#pragma unroll
    for (int m = 0; m < 4; ++m) {
      int r = wr * 64 + m * 16 + llo;
      af[m] = *(const bf16x8*)&sa[r * 32 + ((lhi ^ (r & 3)) << 3)];
    }
#pragma unroll
    for (int n = 0; n < 4; ++n) {
      int c = wc * 64 + (n & 1) * 16 + (n >> 1) * 32 + llo;
      bfr[n] = *(const bf16x8*)&sb[c * 32 + ((lhi ^ (c & 3)) << 3)];
    }

    if (t + 2 < T) stage(t + 2);         // slot (t+2)%3: free (last read t-1)

    __builtin_amdgcn_s_setprio(1);
#pragma unroll
    for (int m = 0; m < 4; ++m)
#pragma unroll
      for (int n = 0; n < 4; ++n)
        acc[m][n] = __builtin_amdgcn_mfma_f32_16x16x32_bf16(af[m], bfr[n], acc[m][n], 0, 0, 0);
    __builtin_amdgcn_s_setprio(0);

    if (t + 2 < T)      asm volatile("s_waitcnt vmcnt(3)" ::: "memory");
    else if (t + 1 < T) asm volatile("s_waitcnt vmcnt(0)" ::: "memory");
    if (t + 1 < T) {
      __builtin_amdgcn_s_barrier();
      __builtin_amdgcn_sched_barrier(0);
      asm volatile("" ::: "memory");
    }
  }

  // epilogue: C/D layout col=lane&15, row=(lane>>4)*4+j
#pragma unroll
  for (int m = 0; m < 4; ++m)
#pragma unroll
    for (int n = 0; n < 4; ++n) {
      const int col = col0 + wc * 64 + (n & 1) * 16 + (n >> 1) * 32 + llo;
      const float bv = bias[col];
      const int rowbase = row0 + wr * 64 + m * 16 + lhi * 4;
      if (MODE == 1) {
#pragma unroll
        for (int j = 0; j < 4; ++j)
          ((float*)Cout)[(size_t)(rowbase + j) * N + col] = acc[m][n][j] + bv;
      } else if (col < 2048) {
#pragma unroll
        for (int j = 0; j < 4; ++j)
          ((bf16*)Cout)[(size_t)(rowbase + j) * N + col] = __float2bfloat16(acc[m][n][j] + bv);
      } else {
        // V columns: write ONLY the transposed vt[(b*16+h)*64+d][s]
        const int hh = (col - 2048) >> 6, d = (col - 2048) & 63;
        const int bb = rowbase >> 11, s0 = rowbase & 2047;
        alignas(8) bf16 tmp[4];
#pragma unroll
        for (int j = 0; j < 4; ++j) tmp[j] = __float2bfloat16(acc[m][n][j] + bv);
        *(uint2*)&vt[((size_t)(bb * 16 + hh) * 64 + d) * 2048 + s0] = *(const uint2*)tmp;
      }
    }
}

// ---------------- causal flash attention (L2-direct K/V, zero barriers) ------
// K+V per (b,h) = 512KB; pair map puts same-(b,h) blocks on one XCD
// (bx&7 == (h*4+b)&7): 8 sets x 512KB = 4MB = one L2. So skip LDS staging
// entirely (Common-mistake #7 / m169): K/V fragments load straight from L2 as
// per-lane 16B chunks. Eliminates staging writes, double-buffering, and ALL
// __syncthreads (lP is wave-private; same-wave ds ordering via lgkmcnt).
// Waves fully independent -> perfect drift. 8 waves x 32 q (hh=0,1), QBLK=256,
// 512 blocks (R10 pair map). No-max softmax (Q pre-scaled), ones-MFMA denom.
__global__ __launch_bounds__(512, 4) void attn(
    const bf16* __restrict__ QKV, const bf16* __restrict__ Vt,
    bf16* __restrict__ O)
{
  const int S = 2048, DM = 3072;
  const int bx = blockIdx.x;
  const int qt = (bx < 256) ? (bx >> 6) : (7 - ((bx - 256) >> 6));
  const int rem = bx & 63, h = rem >> 2, b = rem & 3;
  const int tid = threadIdx.x, wave = tid >> 6, lane = tid & 63;
  const int lhi = lane >> 4, llo = lane & 15;

  __shared__ bf16 lP[8][32 * 64];      // 32 KB, per-wave P [q 32][kv 64]

  const size_t rowb = (size_t)b * S;
  const int q0 = qt * 256;
  const int qw = q0 + wave * 32;
  const int dmax = (qw + 31) >> 6;     // last KV tile this wave needs

  bf16x8 vones;
#pragma unroll
  for (int i = 0; i < 8; ++i) vones[i] = (__bf16)1.0f;

  // global bases (L2-resident working set per (b,h))
  const bf16* Kb = QKV + rowb * DM + 1024 + (size_t)h * 64;      // row kv, col d
  const bf16* Vb = Vt + ((size_t)(b * 16 + h) * 64) * S;         // row d, col kv

  // Q fragments (B operand): col=lane&15 = q-row (per hh), k = kk*32 + lhi*8
  bf16x8 qf[2][2];
#pragma unroll
  for (int hh = 0; hh < 2; ++hh)
#pragma unroll
    for (int kk = 0; kk < 2; ++kk)
      qf[hh][kk] = *(const bf16x8*)&QKV[(rowb + qw + hh * 16 + llo) * DM
                                        + h * 64 + kk * 32 + lhi * 8];

  f32x4 o_acc[2][4] = {};
  f32x4 o_l[2] = {};                   // softmax denom via ones-MFMA

  for (int kt = 0; kt <= dmax; ++kt) {
    // S^T = mfma(K, Q): K fragments straight from L2 (16B/lane, contiguous)
    f32x4 s[2][4] = {};
    __builtin_amdgcn_s_setprio(1);
#pragma unroll
    for (int kk = 0; kk < 2; ++kk)
#pragma unroll
      for (int n = 0; n < 4; ++n) {
        const int kr = n * 16 + llo;
        bf16x8 kf = *(const bf16x8*)&Kb[(size_t)(kt * 64 + kr) * DM + kk * 32 + lhi * 8];
        s[0][n] = __builtin_amdgcn_mfma_f32_16x16x32_bf16(kf, qf[0][kk], s[0][n], 0, 0, 0);
        s[1][n] = __builtin_amdgcn_mfma_f32_16x16x32_bf16(kf, qf[1][kk], s[1][n], 0, 0, 0);
      }
    __builtin_amdgcn_s_setprio(0);

#pragma unroll
    for (int hh = 0; hh < 2; ++hh) {
      // causal mask only when this tile touches hh's diagonal region
      if (kt >= ((qw + hh * 16) >> 6)) {
        const int lim = qw + hh * 16 + llo - kt * 64;
#pragma unroll
        for (int n = 0; n < 4; ++n)
#pragma unroll
          for (int j = 0; j < 4; ++j)
            if (n * 16 + lhi * 4 + j > lim) s[hh][n][j] = -INFINITY;
      }

      // P = exp2(S) -- no online max (fixed m=0; Q pre-scaled)
#pragma unroll
      for (int n = 0; n < 4; ++n)
#pragma unroll
        for (int j = 0; j < 4; ++j)
          s[hh][n][j] = exp2f(s[hh][n][j]);

      // P -> lP[q][kv], 4-elem groups swizzled by q (2-way, free).
      // lP is WAVE-PRIVATE: write->read ordering within the wave is
      // guaranteed by compiler-inserted lgkmcnt. No barrier needed.
#pragma unroll
      for (int n = 0; n < 4; ++n) {
        alignas(8) bf16 tmp[4];
#pragma unroll
        for (int j = 0; j < 4; ++j) tmp[j] = __float2bfloat16(s[hh][n][j]);
        const int g = (n * 4 + lhi) ^ ((llo & 7) << 1);
        *(uint2*)&lP[wave][(hh * 16 + llo) * 64 + g * 4] = *(const uint2*)tmp;
      }
    }

    // O^T += mfma(V^T, P); denom += mfma(ones, P). V fragments from L2.
    __builtin_amdgcn_s_setprio(1);
#pragma unroll
    for (int kk = 0; kk < 2; ++kk) {
      const int g0 = (kk * 8 + lhi * 2) ^ ((llo & 7) << 1);
      bf16x8 pf0 = *(const bf16x8*)&lP[wave][(llo) * 64 + g0 * 4];
      bf16x8 pf1 = *(const bf16x8*)&lP[wave][(16 + llo) * 64 + g0 * 4];
#pragma unroll
      for (int n = 0; n < 4; ++n) {
        const int vr = n * 16 + llo;
        bf16x8 vf = *(const bf16x8*)&Vb[(size_t)vr * S + kt * 64 + kk * 32 + lhi * 8];
        o_acc[0][n] = __builtin_amdgcn_mfma_f32_16x16x32_bf16(vf, pf0, o_acc[0][n], 0, 0, 0);
        o_acc[1][n] = __builtin_amdgcn_mfma_f32_16x16x32_bf16(vf, pf1, o_acc[1][n], 0, 0, 0);
      }
      o_l[0] = __builtin_amdgcn_mfma_f32_16x16x32_bf16(vones, pf0, o_l[0], 0, 0, 0);
      o_l[1] = __builtin_amdgcn_mfma_f32_16x16x32_bf16(vones, pf1, o_l[1], 0, 0, 0);
    }
    __builtin_amdgcn_s_setprio(0);
  }

  // write O: lane owns q = qw + hh*16 + llo
#pragma unroll
  for (int hh = 0; hh < 2; ++hh) {
    const float inv = 1.0f / o_l[hh][0];
    const size_t orow = (rowb + qw + hh * 16 + llo) * 1024 + h * 64;
#pragma unroll
    for (int n = 0; n < 4; ++n) {
      alignas(8) bf16 tmp[4];
#pragma unroll
      for (int j = 0; j < 4; ++j) tmp[j] = __float2bfloat16(o_acc[hh][n][j] * inv);
      *(uint2*)&O[orow + n * 16 + lhi * 4] = *(const uint2*)tmp;
    }
  }
}

extern "C" void kernel_launch(void* const* d_in, const int* in_sizes, int n_in,
                              void* d_out, int out_size, void* d_ws, size_t ws_size,
                              hipStream_t stream) {
  const float* x  = (const float*)d_in[0];
  const float* Wq = (const float*)d_in[1];
  const float* bq = (const float*)d_in[2];
  const float* Wk = (const float*)d_in[3];
  const float* bk = (const float*)d_in[4];
  const float* Wv = (const float*)d_in[5];
  const float* bv = (const float*)d_in[6];
  const float* Wo = (const float*)d_in[7];
  const float* bo = (const float*)d_in[8];

  const int Bb = 4, S = 2048, D = 1024;
  const int M = Bb * S;       // 8192
  const int N3 = 3 * D;       // 3072

  bf16* x16  = (bf16*)d_ws;                    // M*D (reused as attn output)
  bf16* wqkv = x16 + (size_t)M * D;            // 3*D*D
  bf16* wo16 = wqkv + (size_t)3 * D * D;       // D*D
  bf16* qkv  = wo16 + (size_t)D * D;           // M*3D (V third unused)
  bf16* vt   = qkv + (size_t)M * N3;           // M*D
  float* b3  = (float*)(vt + (size_t)M * D);   // 3072 floats
  size_t needed = ((size_t)M * D * 3 + 4 * (size_t)D * D + (size_t)M * N3) * 2 + 3072 * 4;
  if (ws_size < needed) return;

  cvt_bf16<<<(M * D) / (8 * 256), 256, 0, stream>>>(x, x16, M * D);
  prep_w<<<2060, 256, 0, stream>>>(Wq, Wk, Wv, Wo, bq, bk, bv, wqkv, wo16, b3);

  // QKV projection (V transposed in-epilogue): 768 blocks, L2-locality map
  gemm6<0><<<(M / 128) * (N3 / 256), 512, 0, stream>>>(x16, wqkv, b3, qkv, vt, N3, D);
  // causal attention -> x16 (L2-direct K/V, zero barriers): 512 blocks
  attn<<<dim3(512, 1, 1), 512, 0, stream>>>(qkv, vt, x16);
  // output projection: 256 blocks, L2-locality map
  gemm6<1><<<(M / 128) * (D / 256), 512, 0, stream>>>(x16, wo16, bo, d_out, nullptr, D, D);
}

// Round 22
// 167.207 us; speedup vs baseline: 1.5763x; 1.5763x over previous
//
#include <hip/hip_runtime.h>
#include <hip/hip_bf16.h>
#include <math.h>

typedef __hip_bfloat16 bf16;
typedef __attribute__((ext_vector_type(8))) __bf16 bf16x8;
typedef __attribute__((ext_vector_type(4))) float f32x4;

__device__ __forceinline__ void gload_lds16(const void* g, void* l) {
  __builtin_amdgcn_global_load_lds(
      (const __attribute__((address_space(1))) unsigned int*)g,
      (__attribute__((address_space(3))) unsigned int*)l, 16, 0, 0);
}

// ---- merged input/weight conversion + bias concat (ONE launch) ----
// blocks [0,2048): weights (Q pre-scaled by 1/sqrt(HD)*log2(e));
// blocks [2048,2060): bias concat; blocks [2060,6156): x fp32->bf16.
__global__ void prep_all(const float* __restrict__ x, const float* __restrict__ Wq,
                         const float* __restrict__ Wk, const float* __restrict__ Wv,
                         const float* __restrict__ Wo,
                         const float* __restrict__ bq, const float* __restrict__ bk,
                         const float* __restrict__ bv,
                         bf16* __restrict__ x16, bf16* __restrict__ wqkv,
                         bf16* __restrict__ wo16, float* __restrict__ b3) {
  const float QSCL = 0.125f * 1.4426950408889634f;
  const int bi = blockIdx.x;
  if (bi < 2048) {
    const int seg = bi >> 9;                        // 512 blocks per 1M-elem W
    const int idx = ((bi & 511) * 256 + threadIdx.x) * 8;
    const float* src = seg == 0 ? Wq : seg == 1 ? Wk : seg == 2 ? Wv : Wo;
    bf16* dst = seg < 3 ? wqkv + (size_t)seg * 1048576 : wo16;
    const float m = (seg == 0) ? QSCL : 1.0f;
    float4 v0 = *(const float4*)(src + idx);
    float4 v1 = *(const float4*)(src + idx + 4);
    alignas(16) bf16 tmp[8];
    tmp[0] = __float2bfloat16(v0.x * m); tmp[1] = __float2bfloat16(v0.y * m);
    tmp[2] = __float2bfloat16(v0.z * m); tmp[3] = __float2bfloat16(v0.w * m);
    tmp[4] = __float2bfloat16(v1.x * m); tmp[5] = __float2bfloat16(v1.y * m);
    tmp[6] = __float2bfloat16(v1.z * m); tmp[7] = __float2bfloat16(v1.w * m);
    *(uint4*)(dst + idx) = *(const uint4*)tmp;
  } else if (bi < 2060) {
    const int i = (bi - 2048) * 256 + threadIdx.x;
    if (i < 3072)
      b3[i] = i < 1024 ? bq[i] * QSCL : i < 2048 ? bk[i - 1024] : bv[i - 2048];
  } else {
    const int idx = ((bi - 2060) * 256 + threadIdx.x) * 8;
    float4 v0 = *(const float4*)(x + idx);
    float4 v1 = *(const float4*)(x + idx + 4);
    alignas(16) bf16 tmp[8];
    tmp[0] = __float2bfloat16(v0.x); tmp[1] = __float2bfloat16(v0.y);
    tmp[2] = __float2bfloat16(v0.z); tmp[3] = __float2bfloat16(v0.w);
    tmp[4] = __float2bfloat16(v1.x); tmp[5] = __float2bfloat16(v1.y);
    tmp[6] = __float2bfloat16(v1.z); tmp[7] = __float2bfloat16(v1.w);
    *(uint4*)(x16 + idx) = *(const uint4*)tmp;
  }
}

// ---------------- GEMM v6: barrier-minimal ring-3, BK=32, 2 blocks/CU --------
// (frozen from R20) BM=128, BN=256, BK=32. 8 waves (2x4), per-wave 64x64 C.
// SLOT 24KB, ring-3 = 72KB -> 2 blocks/CU = 16 waves/CU. One vmcnt+barrier
// per K-tile (counted vmcnt(3)); swizzle g^=r&3; setprio; L2-locality map.
template<int MODE>
__global__ __launch_bounds__(512, 2) void gemm6(
    const bf16* __restrict__ A, const bf16* __restrict__ Bw,
    const float* __restrict__ bias, void* __restrict__ Cout,
    bf16* __restrict__ vt, int N, int K)
{
  constexpr int SLOT = 12288;            // (128 + 256) * 32 bf16 = 24 KB
  __shared__ bf16 lds[3 * SLOT];         // 72 KB -> 2 blocks/CU
  const int tid = threadIdx.x;
  const int wave = tid >> 6, lane = tid & 63;
  const int lhi = lane >> 4, llo = lane & 15;
  const int wr = wave >> 2, wc = wave & 3;    // 2 x 4 wave grid

  const int xcd = blockIdx.x & 7;
  const int l = blockIdx.x >> 3;
  const int row0 = (xcd * 8 + (l & 7)) * 128;
  const int col0 = (l >> 3) * 256;

  auto stage = [&](int t) {
    bf16* s = &lds[(t % 3) * SLOT];
    const size_t k0 = (size_t)t << 5;
    {
      int i = tid;
      int r = i >> 2, gl = (i & 3) ^ (r & 3);
      gload_lds16(A + (size_t)(row0 + r) * K + k0 + gl * 8, s + i * 8);
    }
#pragma unroll
    for (int j = 0; j < 2; ++j) {
      int i = j * 512 + tid;
      int r = i >> 2, gl = (i & 3) ^ (r & 3);
      gload_lds16(Bw + (size_t)(col0 + r) * K + k0 + gl * 8, s + 4096 + i * 8);
    }
  };

  f32x4 acc[4][4] = {};
  const int T = K >> 5;

  stage(0); stage(1);
  asm volatile("s_waitcnt vmcnt(3)" ::: "memory");   // tile 0 complete
  __builtin_amdgcn_s_barrier();
  __builtin_amdgcn_sched_barrier(0);

  for (int t = 0; t < T; ++t) {
    const bf16* sa = &lds[(t % 3) * SLOT];
    const bf16* sb = sa + 4096;

    bf16x8 af[4], bfr[4];
#pragma unroll
    for (int m = 0; m < 4; ++m) {
      int r = wr * 64 + m * 16 + llo;
      af[m] = *(const bf16x8*)&sa[r * 32 + ((lhi ^ (r & 3)) << 3)];
    }
#pragma unroll
    for (int n = 0; n < 4; ++n) {
      int c = wc * 64 + (n & 1) * 16 + (n >> 1) * 32 + llo;
      bfr[n] = *(const bf16x8*)&sb[c * 32 + ((lhi ^ (c & 3)) << 3)];
    }

    if (t + 2 < T) stage(t + 2);         // slot (t+2)%3: free (last read t-1)

    __builtin_amdgcn_s_setprio(1);
#pragma unroll
    for (int m = 0; m < 4; ++m)
#pragma unroll
      for (int n = 0; n < 4; ++n)
        acc[m][n] = __builtin_amdgcn_mfma_f32_16x16x32_bf16(af[m], bfr[n], acc[m][n], 0, 0, 0);
    __builtin_amdgcn_s_setprio(0);

    if (t + 2 < T)      asm volatile("s_waitcnt vmcnt(3)" ::: "memory");
    else if (t + 1 < T) asm volatile("s_waitcnt vmcnt(0)" ::: "memory");
    if (t + 1 < T) {
      __builtin_amdgcn_s_barrier();
      __builtin_amdgcn_sched_barrier(0);
      asm volatile("" ::: "memory");
    }
  }

  // epilogue: C/D layout col=lane&15, row=(lane>>4)*4+j
#pragma unroll
  for (int m = 0; m < 4; ++m)
#pragma unroll
    for (int n = 0; n < 4; ++n) {
      const int col = col0 + wc * 64 + (n & 1) * 16 + (n >> 1) * 32 + llo;
      const float bv = bias[col];
      const int rowbase = row0 + wr * 64 + m * 16 + lhi * 4;
      if (MODE == 1) {
#pragma unroll
        for (int j = 0; j < 4; ++j)
          ((float*)Cout)[(size_t)(rowbase + j) * N + col] = acc[m][n][j] + bv;
      } else if (col < 2048) {
#pragma unroll
        for (int j = 0; j < 4; ++j)
          ((bf16*)Cout)[(size_t)(rowbase + j) * N + col] = __float2bfloat16(acc[m][n][j] + bv);
      } else {
        // V columns: write ONLY the transposed vt[(b*16+h)*64+d][s]
        const int hh = (col - 2048) >> 6, d = (col - 2048) & 63;
        const int bb = rowbase >> 11, s0 = rowbase & 2047;
        alignas(8) bf16 tmp[4];
#pragma unroll
        for (int j = 0; j < 4; ++j) tmp[j] = __float2bfloat16(acc[m][n][j] + bv);
        *(uint2*)&vt[((size_t)(bb * 16 + hh) * 64 + d) * 2048 + s0] = *(const uint2*)tmp;
      }
    }
}

// ---------------- causal flash attention (R20: R10 config + T5 setprio) ------
// QBLK=256: 8 waves x 32 q-rows (hh=0,1 share every K/V ds_read). Grid 512
// blocks, balanced pair map, 64KB LDS -> 2 blocks/CU = 16 waves/CU.
// LDS staging via global_load_lds (wave-coalesced 1KB bursts -- R21 proved
// per-lane L2-direct loses 2.3x to de-coalescing). No-max softmax
// (Q pre-scaled), ones-MFMA denominator, setprio around MFMA clusters.
__global__ __launch_bounds__(512, 4) void attn(
    const bf16* __restrict__ QKV, const bf16* __restrict__ Vt,
    bf16* __restrict__ O)
{
  const int S = 2048, DM = 3072;
  const int bx = blockIdx.x;
  const int qt = (bx < 256) ? (bx >> 6) : (7 - ((bx - 256) >> 6));
  const int rem = bx & 63, h = rem >> 2, b = rem & 3;
  const int tid = threadIdx.x, wave = tid >> 6, lane = tid & 63;
  const int lhi = lane >> 4, llo = lane & 15;

  __shared__ bf16 lK[2][64 * 64];      // 16 KB
  __shared__ bf16 lV[2][64 * 64];      // 16 KB
  __shared__ bf16 lP[8][32 * 64];      // 32 KB, per-wave P [q 32][kv 64]

  const size_t rowb = (size_t)b * S;
  const int q0 = qt * 256;
  const int nkt = 4 * qt + 4;
  const int qw = q0 + wave * 32;
  const int dmax = (qw + 31) >> 6;     // last KV tile this wave needs

  bf16x8 vones;
#pragma unroll
  for (int i = 0; i < 8; ++i) vones[i] = (__bf16)1.0f;

  auto stageKV = [&](int buf, int kt) {
    const int i = tid;                          // 512 x 16B chunks per tile
    const int r = i >> 3;
    const int ce = ((i & 7) * 8) ^ ((r & 7) << 3);
    gload_lds16(&QKV[(rowb + (size_t)kt * 64 + r) * DM + 1024 + h * 64 + ce],
                &lK[buf][i * 8]);
    gload_lds16(&Vt[((size_t)(b * 16 + h) * 64 + r) * S + kt * 64 + ce],
                &lV[buf][i * 8]);
  };

  // Q fragments (B operand): col=lane&15 = q-row (per hh), k = kk*32 + lhi*8
  bf16x8 qf[2][2];
#pragma unroll
  for (int hh = 0; hh < 2; ++hh)
#pragma unroll
    for (int kk = 0; kk < 2; ++kk)
      qf[hh][kk] = *(const bf16x8*)&QKV[(rowb + qw + hh * 16 + llo) * DM
                                        + h * 64 + kk * 32 + lhi * 8];

  f32x4 o_acc[2][4] = {};
  f32x4 o_l[2] = {};                   // softmax denom via ones-MFMA

  stageKV(0, 0);
  for (int kt = 0; kt < nkt; ++kt) {
    __syncthreads();                   // buf kt&1 staged
    if (kt + 1 < nkt) stageKV((kt + 1) & 1, kt + 1);
    if (kt > dmax) continue;           // beyond this wave's diagonal
    const int buf = kt & 1;

    // S^T = mfma(K, Q): s[hh][n][j] = S[kv = n*16+lhi*4+j][q = qw+hh*16+llo]
    f32x4 s[2][4] = {};
    __builtin_amdgcn_s_setprio(1);
#pragma unroll
    for (int kk = 0; kk < 2; ++kk)
#pragma unroll
      for (int n = 0; n < 4; ++n) {
        const int kr = n * 16 + llo;
        bf16x8 kf = *(const bf16x8*)&lK[buf][kr * 64 + ((kk * 32 + lhi * 8) ^ ((kr & 7) << 3))];
        s[0][n] = __builtin_amdgcn_mfma_f32_16x16x32_bf16(kf, qf[0][kk], s[0][n], 0, 0, 0);
        s[1][n] = __builtin_amdgcn_mfma_f32_16x16x32_bf16(kf, qf[1][kk], s[1][n], 0, 0, 0);
      }
    __builtin_amdgcn_s_setprio(0);

#pragma unroll
    for (int hh = 0; hh < 2; ++hh) {
      // causal mask only when this tile touches hh's diagonal region
      if (kt >= ((qw + hh * 16) >> 6)) {
        const int lim = qw + hh * 16 + llo - kt * 64;
#pragma unroll
        for (int n = 0; n < 4; ++n)
#pragma unroll
          for (int j = 0; j < 4; ++j)
            if (n * 16 + lhi * 4 + j > lim) s[hh][n][j] = -INFINITY;
      }

      // P = exp2(S) -- no online max (fixed m=0; Q pre-scaled)
#pragma unroll
      for (int n = 0; n < 4; ++n)
#pragma unroll
        for (int j = 0; j < 4; ++j)
          s[hh][n][j] = exp2f(s[hh][n][j]);

      // P -> lP[q][kv], 4-elem groups swizzled by q (2-way, free)
#pragma unroll
      for (int n = 0; n < 4; ++n) {
        alignas(8) bf16 tmp[4];
#pragma unroll
        for (int j = 0; j < 4; ++j) tmp[j] = __float2bfloat16(s[hh][n][j]);
        const int g = (n * 4 + lhi) ^ ((llo & 7) << 1);
        *(uint2*)&lP[wave][(hh * 16 + llo) * 64 + g * 4] = *(const uint2*)tmp;
      }
    }

    // O^T += mfma(V^T, P); denom += mfma(ones, P). vf shared by both hh.
    __builtin_amdgcn_s_setprio(1);
#pragma unroll
    for (int kk = 0; kk < 2; ++kk) {
      const int g0 = (kk * 8 + lhi * 2) ^ ((llo & 7) << 1);
      bf16x8 pf0 = *(const bf16x8*)&lP[wave][(llo) * 64 + g0 * 4];
      bf16x8 pf1 = *(const bf16x8*)&lP[wave][(16 + llo) * 64 + g0 * 4];
#pragma unroll
      for (int n = 0; n < 4; ++n) {
        const int vr = n * 16 + llo;
        bf16x8 vf = *(const bf16x8*)&lV[buf][vr * 64 + ((kk * 32 + lhi * 8) ^ ((vr & 7) << 3))];
        o_acc[0][n] = __builtin_amdgcn_mfma_f32_16x16x32_bf16(vf, pf0, o_acc[0][n], 0, 0, 0);
        o_acc[1][n] = __builtin_amdgcn_mfma_f32_16x16x32_bf16(vf, pf1, o_acc[1][n], 0, 0, 0);
      }
      o_l[0] = __builtin_amdgcn_mfma_f32_16x16x32_bf16(vones, pf0, o_l[0], 0, 0, 0);
      o_l[1] = __builtin_amdgcn_mfma_f32_16x16x32_bf16(vones, pf1, o_l[1], 0, 0, 0);
    }
    __builtin_amdgcn_s_setprio(0);
  }

  // write O: lane owns q = qw + hh*16 + llo
#pragma unroll
  for (int hh = 0; hh < 2; ++hh) {
    const float inv = 1.0f / o_l[hh][0];
    const size_t orow = (rowb + qw + hh * 16 + llo) * 1024 + h * 64;
#pragma unroll
    for (int n = 0; n < 4; ++n) {
      alignas(8) bf16 tmp[4];
#pragma unroll
      for (int j = 0; j < 4; ++j) tmp[j] = __float2bfloat16(o_acc[hh][n][j] * inv);
      *(uint2*)&O[orow + n * 16 + lhi * 4] = *(const uint2*)tmp;
    }
  }
}

extern "C" void kernel_launch(void* const* d_in, const int* in_sizes, int n_in,
                              void* d_out, int out_size, void* d_ws, size_t ws_size,
                              hipStream_t stream) {
  const float* x  = (const float*)d_in[0];
  const float* Wq = (const float*)d_in[1];
  const float* bq = (const float*)d_in[2];
  const float* Wk = (const float*)d_in[3];
  const float* bk = (const float*)d_in[4];
  const float* Wv = (const float*)d_in[5];
  const float* bv = (const float*)d_in[6];
  const float* Wo = (const float*)d_in[7];
  const float* bo = (const float*)d_in[8];

  const int Bb = 4, S = 2048, D = 1024;
  const int M = Bb * S;       // 8192
  const int N3 = 3 * D;       // 3072

  bf16* x16  = (bf16*)d_ws;                    // M*D (reused as attn output)
  bf16* wqkv = x16 + (size_t)M * D;            // 3*D*D
  bf16* wo16 = wqkv + (size_t)3 * D * D;       // D*D
  bf16* qkv  = wo16 + (size_t)D * D;           // M*3D (V third unused)
  bf16* vt   = qkv + (size_t)M * N3;           // M*D
  float* b3  = (float*)(vt + (size_t)M * D);   // 3072 floats
  size_t needed = ((size_t)M * D * 3 + 4 * (size_t)D * D + (size_t)M * N3) * 2 + 3072 * 4;
  if (ws_size < needed) return;

  // one merged prep launch: weights + bias + x conversion
  prep_all<<<2060 + (M * D) / (8 * 256), 256, 0, stream>>>(
      x, Wq, Wk, Wv, Wo, bq, bk, bv, x16, wqkv, wo16, b3);

  // QKV projection (V transposed in-epilogue): 768 blocks, L2-locality map
  gemm6<0><<<(M / 128) * (N3 / 256), 512, 0, stream>>>(x16, wqkv, b3, qkv, vt, N3, D);
  // causal attention -> x16 (R20 config): 8 waves x 32 q, 512 blocks
  attn<<<dim3(512, 1, 1), 512, 0, stream>>>(qkv, vt, x16);
  // output projection: 256 blocks, L2-locality map
  gemm6<1><<<(M / 128) * (D / 256), 512, 0, stream>>>(x16, wo16, bo, d_out, nullptr, D, D);
}